// Round 1
// baseline (2204.567 us; speedup 1.0000x reference)
//
#include <hip/hip_runtime.h>
#include <math.h>

// Problem constants (fixed by setup_inputs)
#define B_  32
#define N_  20000
#define C_  8
#define E_  512
#define H_  8
#define DH  64
#define SCALE 0.125f   // 1/sqrt(64)

// ---------------------------------------------------------------------------
// K1a: q(c,b,f) = sum_e x(b,e) * Wq[c][f,e] + bq[c][f]
// grid = C*B blocks, 256 threads (4 waves); wave-per-output-row dot products.
// ---------------------------------------------------------------------------
__global__ void k_q(const float* __restrict__ x, const float* __restrict__ Wq,
                    const float* __restrict__ bq, float* __restrict__ q) {
    int c = blockIdx.x / B_;
    int b = blockIdx.x % B_;
    __shared__ float xs[E_];
    int tid = threadIdx.x;
    for (int i = tid; i < E_; i += 256) xs[i] = x[b * E_ + i];
    __syncthreads();
    int wave = tid >> 6, lane = tid & 63;
    const float* W = Wq + (size_t)c * E_ * E_;
    for (int f = wave; f < E_; f += 4) {
        const float* row = W + (size_t)f * E_;
        float s = 0.f;
        #pragma unroll
        for (int e0 = 0; e0 < E_; e0 += 64) s += row[e0 + lane] * xs[e0 + lane];
        #pragma unroll
        for (int off = 32; off > 0; off >>= 1) s += __shfl_down(s, off, 64);
        if (lane == 0) q[((size_t)c * B_ + b) * E_ + f] = s + bq[c * E_ + f];
    }
}

// ---------------------------------------------------------------------------
// K1b: u(c,b,h,e) = sum_d q(c,b,h*64+d) * Wk[c][h*64+d, e]
//      qb(c,b,h)  = sum_d q(c,b,h*64+d) * bk[c][h*64+d]
// grid = C*B*H blocks, 64 threads (1 wave).
// ---------------------------------------------------------------------------
__global__ void k_u(const float* __restrict__ q, const float* __restrict__ Wk,
                    const float* __restrict__ bk, float* __restrict__ u,
                    float* __restrict__ qb) {
    int idx = blockIdx.x;             // c*(B*H) + b*H + h
    int c  = idx / (B_ * H_);
    int bh = idx % (B_ * H_);
    int b  = bh / H_;
    int h  = bh % H_;
    int lane = threadIdx.x;
    __shared__ float qs[DH];
    float qv = q[((size_t)c * B_ + b) * E_ + h * DH + lane];
    qs[lane] = qv;
    float s = qv * bk[c * E_ + h * DH + lane];
    #pragma unroll
    for (int off = 32; off > 0; off >>= 1) s += __shfl_down(s, off, 64);
    __syncthreads();
    const float* W = Wk + (size_t)c * E_ * E_ + (size_t)(h * DH) * E_;
    float* urow = u + (size_t)idx * E_;
    for (int e0 = 0; e0 < E_; e0 += 64) {
        float acc = 0.f;
        #pragma unroll 8
        for (int d = 0; d < DH; ++d) acc += qs[d] * W[(size_t)d * E_ + e0 + lane];
        urow[e0 + lane] = acc;
    }
    if (lane == 0) qb[idx] = s;
}

// ---------------------------------------------------------------------------
// K2: per-class scores GEMM + mask + exp.
//   S(m,n) = member(c,n) ? exp(scale*(u_c(m,:)·A(n,:) + qb_c(m))) : 0
//   M = B*H = 256, N = 20000, K = 512. fp32, 64x64x16 tiles, 4x4 per thread.
// Scores are bounded (|s| ~< 1.5 for these inputs) so no max-subtraction:
// exp is monotone, ranking is preserved exactly.
// ---------------------------------------------------------------------------
#define BM 64
#define BN 64
#define BK 16
#define LDSP 68   // +4 pad: breaks staging-write bank conflicts, keeps 16B align

__global__ __launch_bounds__(256) void k_scores(
        const float* __restrict__ u, const float* __restrict__ qb,
        const float* __restrict__ A, const int* __restrict__ mask,
        float* __restrict__ S, int c) {
    __shared__ __align__(16) float Us[BK][LDSP];
    __shared__ __align__(16) float As[BK][LDSP];
    int tid = threadIdx.x;
    int m0 = blockIdx.y * BM;
    int n0 = blockIdx.x * BN;
    const float* Uc = u + (size_t)c * (B_ * H_) * E_;
    int lr = tid >> 4;   // 0..15 (row group for staging)
    int lk = tid & 15;   // 0..15 (k for staging)
    int ty = tid >> 4;   // 0..15 (m group, 4 rows each)
    int tx = tid & 15;   // 0..15 (n group, 4 cols each)
    float acc[4][4] = {};
    for (int k0 = 0; k0 < E_; k0 += BK) {
        #pragma unroll
        for (int p = 0; p < 4; ++p) {
            int r = lr + p * 16;
            Us[lk][r] = Uc[(size_t)(m0 + r) * E_ + k0 + lk];
            int n = n0 + r;
            As[lk][r] = (n < N_) ? A[(size_t)n * E_ + k0 + lk] : 0.f;
        }
        __syncthreads();
        #pragma unroll
        for (int k = 0; k < BK; ++k) {
            float4 a4 = *((const float4*)(&Us[k][0]) + ty);
            float4 b4 = *((const float4*)(&As[k][0]) + tx);
            float a[4] = {a4.x, a4.y, a4.z, a4.w};
            float b[4] = {b4.x, b4.y, b4.z, b4.w};
            #pragma unroll
            for (int i = 0; i < 4; ++i)
                #pragma unroll
                for (int j = 0; j < 4; ++j)
                    acc[i][j] += a[i] * b[j];
        }
        __syncthreads();
    }
    #pragma unroll
    for (int i = 0; i < 4; ++i) {
        int m = m0 + ty * 4 + i;
        float qbm = qb[c * (B_ * H_) + m];
        #pragma unroll
        for (int j = 0; j < 4; ++j) {
            int n = n0 + tx * 4 + j;
            if (n < N_) {
                float sc = SCALE * (acc[i][j] + qbm);
                float ev = mask[(size_t)n * C_ + c] ? __expf(sc) : 0.f;
                S[(size_t)m * N_ + n] = ev;
            }
        }
    }
}

// ---------------------------------------------------------------------------
// K2b: Z(m) = sum_n S(m,n). grid = B*H blocks.
// ---------------------------------------------------------------------------
__global__ void k_zred(const float* __restrict__ S, float* __restrict__ Z, int c) {
    int m = blockIdx.x;
    int tid = threadIdx.x;
    const float* row = S + (size_t)m * N_;
    float s = 0.f;
    for (int n = tid; n < N_; n += 256) s += row[n];
    __shared__ float red[256];
    red[tid] = s;
    __syncthreads();
    for (int w = 128; w >= 1; w >>= 1) {
        if (tid < w) red[tid] += red[tid + w];
        __syncthreads();
    }
    if (tid == 0) Z[c * (B_ * H_) + m] = red[0];
}

// ---------------------------------------------------------------------------
// K3: attn(b,n) = (1/H) * sum_h S(b*H+h, n) / Z(b*H+h)
// ---------------------------------------------------------------------------
__global__ void k_attn(const float* __restrict__ S, const float* __restrict__ Z,
                       float* __restrict__ attn, int c) {
    int idx = blockIdx.x * 256 + threadIdx.x;
    if (idx >= B_ * N_) return;
    int b = idx / N_;
    int n = idx - b * N_;
    float s = 0.f;
    #pragma unroll
    for (int h = 0; h < H_; ++h) {
        float z = Z[c * (B_ * H_) + b * H_ + h];
        s += S[(size_t)(b * H_ + h) * N_ + n] / z;
    }
    attn[idx] = s * (1.0f / H_);
}

// ---------------------------------------------------------------------------
// K4: top-ns per (b) for class c. Iterative block-argmax; jax tie-breaking
// (equal values -> lower index). Writes indices (as float) and weights.
// ---------------------------------------------------------------------------
__global__ void k_topk(const float* __restrict__ attn, float* __restrict__ out,
                       int c, int ns) {
    int b = blockIdx.x;
    int tid = threadIdx.x;
    const float* row = attn + (size_t)b * N_;
    __shared__ float sv[256];
    __shared__ int   si[256];
    __shared__ int   selIdx[8];
    __shared__ float selVal[8];
    for (int j = 0; j < ns; ++j) {
        float bv = -1.f;
        int   bi = N_;
        for (int n = tid; n < N_; n += 256) {
            bool skip = false;
            for (int t = 0; t < j; ++t)
                if (selIdx[t] == n) skip = true;
            float v = row[n];
            if (!skip && (v > bv || (v == bv && n < bi))) { bv = v; bi = n; }
        }
        sv[tid] = bv; si[tid] = bi;
        __syncthreads();
        for (int w = 128; w >= 1; w >>= 1) {
            if (tid < w) {
                float v2 = sv[tid + w]; int i2 = si[tid + w];
                if (v2 > sv[tid] || (v2 == sv[tid] && i2 < si[tid])) {
                    sv[tid] = v2; si[tid] = i2;
                }
            }
            __syncthreads();
        }
        if (tid == 0) { selIdx[j] = si[0]; selVal[j] = sv[0]; }
        __syncthreads();
    }
    if (tid == 0) {
        for (int j = 0; j < ns; ++j) {
            out[((size_t)b * C_ + c) * ns + j] = (float)selIdx[j];
            out[(size_t)B_ * C_ * ns + ((size_t)b * C_ + c) * ns + j] = selVal[j];
        }
    }
}

// ---------------------------------------------------------------------------
extern "C" void kernel_launch(void* const* d_in, const int* in_sizes, int n_in,
                              void* d_out, int out_size, void* d_ws, size_t ws_size,
                              hipStream_t stream) {
    const float* x    = (const float*)d_in[0];  // (B,E)
    const float* A    = (const float*)d_in[1];  // (N,E)
    const int*   mask = (const int*)  d_in[2];  // (N,C) bool as int32
    const float* Wq   = (const float*)d_in[3];  // (C,E,E)
    const float* bq   = (const float*)d_in[4];  // (C,E)
    const float* Wk   = (const float*)d_in[5];  // (C,E,E)
    const float* bk   = (const float*)d_in[6];  // (C,E)
    float* out = (float*)d_out;

    int ns = out_size / (2 * B_ * C_);          // = n_samples

    // Workspace layout (floats): ~27.8 MB total
    float* ws = (float*)d_ws;
    float* q    = ws;                                   // C*B*E      = 131072
    float* u    = q    + (size_t)C_ * B_ * E_;          // C*B*H*E    = 1048576
    float* qb   = u    + (size_t)C_ * B_ * H_ * E_;     // C*B*H      = 2048
    float* Z    = qb   + (size_t)C_ * B_ * H_;          // C*B*H      = 2048
    float* S    = Z    + (size_t)C_ * B_ * H_;          // B*H*N      = 5120000
    float* attn = S    + (size_t)B_ * H_ * N_;          // B*N        = 640000

    k_q<<<C_ * B_, 256, 0, stream>>>(x, Wq, bq, q);
    k_u<<<C_ * B_ * H_, 64, 0, stream>>>(q, Wk, bk, u, qb);

    dim3 gridS((N_ + BN - 1) / BN, (B_ * H_) / BM);
    for (int c = 0; c < C_; ++c) {
        k_scores<<<gridS, 256, 0, stream>>>(u, qb, A, mask, S, c);
        k_zred<<<B_ * H_, 256, 0, stream>>>(S, Z, c);
        k_attn<<<(B_ * N_ + 255) / 256, 256, 0, stream>>>(S, Z, attn, c);
        k_topk<<<B_, 256, 0, stream>>>(attn, out, c, ns);
    }
}

// Round 2
// 928.886 us; speedup vs baseline: 2.3733x; 2.3733x over previous
//
#include <hip/hip_runtime.h>
#include <math.h>

// Problem constants (fixed by setup_inputs)
#define B_  32
#define N_  20000
#define C_  8
#define E_  512
#define H_  8
#define DH  64
#define SCALE 0.125f   // 1/sqrt(64)

#define CHUNK 512
#define NCH   40       // ceil(20000/512)

// ---------------------------------------------------------------------------
// K1a: q(c,b,f) = sum_e x(b,e) * Wq[c][f,e] + bq[c][f]
// ---------------------------------------------------------------------------
__global__ void k_q(const float* __restrict__ x, const float* __restrict__ Wq,
                    const float* __restrict__ bq, float* __restrict__ q) {
    int c = blockIdx.x / B_;
    int b = blockIdx.x % B_;
    __shared__ float xs[E_];
    int tid = threadIdx.x;
    for (int i = tid; i < E_; i += 256) xs[i] = x[b * E_ + i];
    __syncthreads();
    int wave = tid >> 6, lane = tid & 63;
    const float* W = Wq + (size_t)c * E_ * E_;
    for (int f = wave; f < E_; f += 4) {
        const float* row = W + (size_t)f * E_;
        float s = 0.f;
        #pragma unroll
        for (int e0 = 0; e0 < E_; e0 += 64) s += row[e0 + lane] * xs[e0 + lane];
        #pragma unroll
        for (int off = 32; off > 0; off >>= 1) s += __shfl_down(s, off, 64);
        if (lane == 0) q[((size_t)c * B_ + b) * E_ + f] = s + bq[c * E_ + f];
    }
}

// ---------------------------------------------------------------------------
// K1b: u(c,b,h,e) = sum_d q(c,b,h*64+d) * Wk[c][h*64+d, e];  qb = q·bk per head
// ---------------------------------------------------------------------------
__global__ void k_u(const float* __restrict__ q, const float* __restrict__ Wk,
                    const float* __restrict__ bk, float* __restrict__ u,
                    float* __restrict__ qb) {
    int idx = blockIdx.x;             // c*(B*H) + b*H + h
    int c  = idx / (B_ * H_);
    int bh = idx % (B_ * H_);
    int b  = bh / H_;
    int h  = bh % H_;
    int lane = threadIdx.x;
    __shared__ float qs[DH];
    float qv = q[((size_t)c * B_ + b) * E_ + h * DH + lane];
    qs[lane] = qv;
    float s = qv * bk[c * E_ + h * DH + lane];
    #pragma unroll
    for (int off = 32; off > 0; off >>= 1) s += __shfl_down(s, off, 64);
    __syncthreads();
    const float* W = Wk + (size_t)c * E_ * E_ + (size_t)(h * DH) * E_;
    float* urow = u + (size_t)idx * E_;
    for (int e0 = 0; e0 < E_; e0 += 64) {
        float acc = 0.f;
        #pragma unroll 8
        for (int d = 0; d < DH; ++d) acc += qs[d] * W[(size_t)d * E_ + e0 + lane];
        urow[e0 + lane] = acc;
    }
    if (lane == 0) qb[idx] = s;
}

// ---------------------------------------------------------------------------
// K2: per-class scores GEMM + mask + exp.  S(m,n) for class z-slice.
//   M = B*H = 256, N = 20000, K = 512. fp32, 64x64x16 tiles, 4x4 per thread.
// ---------------------------------------------------------------------------
#define BM 64
#define BN 64
#define BK 16
#define LDSP 68
#define SSZ ((size_t)B_ * H_ * N_)   // per-class S floats

__global__ __launch_bounds__(256) void k_scores(
        const float* __restrict__ u, const float* __restrict__ qb,
        const float* __restrict__ A, const int* __restrict__ mask,
        float* __restrict__ S, int c0) {
    __shared__ __align__(16) float Us[BK][LDSP];
    __shared__ __align__(16) float As[BK][LDSP];
    int z = blockIdx.z;
    int c = c0 + z;
    float* Sc = S + (size_t)z * SSZ;
    int tid = threadIdx.x;
    int m0 = blockIdx.y * BM;
    int n0 = blockIdx.x * BN;
    const float* Uc = u + (size_t)c * (B_ * H_) * E_;
    int lr = tid >> 4;
    int lk = tid & 15;
    int ty = tid >> 4;
    int tx = tid & 15;
    float acc[4][4] = {};
    for (int k0 = 0; k0 < E_; k0 += BK) {
        #pragma unroll
        for (int p = 0; p < 4; ++p) {
            int r = lr + p * 16;
            Us[lk][r] = Uc[(size_t)(m0 + r) * E_ + k0 + lk];
            int n = n0 + r;
            As[lk][r] = (n < N_) ? A[(size_t)n * E_ + k0 + lk] : 0.f;
        }
        __syncthreads();
        #pragma unroll
        for (int k = 0; k < BK; ++k) {
            float4 a4 = *((const float4*)(&Us[k][0]) + ty);
            float4 b4 = *((const float4*)(&As[k][0]) + tx);
            float a[4] = {a4.x, a4.y, a4.z, a4.w};
            float b[4] = {b4.x, b4.y, b4.z, b4.w};
            #pragma unroll
            for (int i = 0; i < 4; ++i)
                #pragma unroll
                for (int j = 0; j < 4; ++j)
                    acc[i][j] += a[i] * b[j];
        }
        __syncthreads();
    }
    #pragma unroll
    for (int i = 0; i < 4; ++i) {
        int m = m0 + ty * 4 + i;
        float qbm = qb[c * (B_ * H_) + m];
        #pragma unroll
        for (int j = 0; j < 4; ++j) {
            int n = n0 + tx * 4 + j;
            if (n < N_) {
                float sc = SCALE * (acc[i][j] + qbm);
                float ev = mask[(size_t)n * C_ + c] ? __expf(sc) : 0.f;
                Sc[(size_t)m * N_ + n] = ev;
            }
        }
    }
}

// ---------------------------------------------------------------------------
// K2b: Z(m) = sum_n S(m,n). grid = (B*H, z)
// ---------------------------------------------------------------------------
__global__ void k_zred(const float* __restrict__ S, float* __restrict__ Z, int c0) {
    int m = blockIdx.x;
    int z = blockIdx.y;
    int tid = threadIdx.x;
    const float* row = S + (size_t)z * SSZ + (size_t)m * N_;
    float s = 0.f;
    for (int n = tid; n < N_; n += 256) s += row[n];
    __shared__ float red[256];
    red[tid] = s;
    __syncthreads();
    for (int w = 128; w >= 1; w >>= 1) {
        if (tid < w) red[tid] += red[tid + w];
        __syncthreads();
    }
    if (tid == 0) Z[(c0 + z) * (B_ * H_) + m] = red[0];
}

// ---------------------------------------------------------------------------
// K3: fused head-average + chunk-local top-ns.
// grid (NCH, B, z), 256 threads. Each block: 512-wide chunk of n for one b.
// Writes ns (value,index) candidates per (z,b,chunk).
// ---------------------------------------------------------------------------
__global__ __launch_bounds__(256) void k_topk1(
        const float* __restrict__ S, const float* __restrict__ Z,
        float2* __restrict__ cand, int c0, int ns) {
    int chunk = blockIdx.x, b = blockIdx.y, z = blockIdx.z;
    const float* Sc = S + (size_t)z * SSZ;
    int tid = threadIdx.x;
    __shared__ float zr[H_];
    if (tid < H_) zr[tid] = 1.0f / Z[(c0 + z) * (B_ * H_) + b * H_ + tid];
    __syncthreads();
    int n0 = chunk * CHUNK;
    float v[2]; int ix[2];
    #pragma unroll
    for (int s = 0; s < 2; ++s) {
        int n = n0 + tid + s * 256;
        float a = -1.f;
        if (n < N_) {
            a = 0.f;
            #pragma unroll
            for (int h = 0; h < H_; ++h)
                a += Sc[(size_t)(b * H_ + h) * N_ + n] * zr[h];
            a *= (1.0f / H_);
        }
        v[s] = a; ix[s] = (n < N_) ? n : N_;
    }
    __shared__ float sv[256];
    __shared__ int   si[256];
    __shared__ int   win;
    for (int j = 0; j < ns; ++j) {
        float bv; int bi;
        if (v[0] > v[1] || (v[0] == v[1] && ix[0] < ix[1])) { bv = v[0]; bi = ix[0]; }
        else                                                 { bv = v[1]; bi = ix[1]; }
        sv[tid] = bv; si[tid] = bi;
        __syncthreads();
        for (int w = 128; w >= 1; w >>= 1) {
            if (tid < w) {
                float v2 = sv[tid + w]; int i2 = si[tid + w];
                if (v2 > sv[tid] || (v2 == sv[tid] && i2 < si[tid])) {
                    sv[tid] = v2; si[tid] = i2;
                }
            }
            __syncthreads();
        }
        if (tid == 0) {
            cand[(((size_t)z * B_ + b) * NCH + chunk) * ns + j] =
                make_float2(sv[0], (float)si[0]);
            win = si[0];
        }
        __syncthreads();
        if (ix[0] == win) v[0] = -2.f;
        if (ix[1] == win) v[1] = -2.f;
        __syncthreads();
    }
}

// ---------------------------------------------------------------------------
// K4: merge NCH*ns candidates -> final top-ns per (b, class). grid (B, z).
// ---------------------------------------------------------------------------
__global__ __launch_bounds__(256) void k_topk2(
        const float2* __restrict__ cand, float* __restrict__ out, int c0, int ns) {
    int b = blockIdx.x, z = blockIdx.y;
    int c = c0 + z;
    int tid = threadIdx.x;
    int ncand = NCH * ns;
    const float2* cb = cand + ((size_t)z * B_ + b) * ncand;
    float v = -3.f; int ix = N_ + 1;
    if (tid < ncand) { float2 e = cb[tid]; v = e.x; ix = (int)e.y; }
    __shared__ float sv[256];
    __shared__ int   si[256];
    __shared__ int   win;
    for (int j = 0; j < ns; ++j) {
        sv[tid] = v; si[tid] = ix;
        __syncthreads();
        for (int w = 128; w >= 1; w >>= 1) {
            if (tid < w) {
                float v2 = sv[tid + w]; int i2 = si[tid + w];
                if (v2 > sv[tid] || (v2 == sv[tid] && i2 < si[tid])) {
                    sv[tid] = v2; si[tid] = i2;
                }
            }
            __syncthreads();
        }
        if (tid == 0) {
            out[((size_t)b * C_ + c) * ns + j] = (float)si[0];
            out[(size_t)B_ * C_ * ns + ((size_t)b * C_ + c) * ns + j] = sv[0];
            win = si[0];
        }
        __syncthreads();
        if (ix == win) v = -3.f;
        __syncthreads();
    }
}

// ---------------------------------------------------------------------------
extern "C" void kernel_launch(void* const* d_in, const int* in_sizes, int n_in,
                              void* d_out, int out_size, void* d_ws, size_t ws_size,
                              hipStream_t stream) {
    const float* x    = (const float*)d_in[0];  // (B,E)
    const float* A    = (const float*)d_in[1];  // (N,E)
    const int*   mask = (const int*)  d_in[2];  // (N,C)
    const float* Wq   = (const float*)d_in[3];  // (C,E,E)
    const float* bq   = (const float*)d_in[4];  // (C,E)
    const float* Wk   = (const float*)d_in[5];  // (C,E,E)
    const float* bk   = (const float*)d_in[6];  // (C,E)
    float* out = (float*)d_out;

    int ns = out_size / (2 * B_ * C_);          // = n_samples (5)

    // Workspace layout (floats)
    float* ws = (float*)d_ws;
    float* q    = ws;                                   // C*B*E
    float* u    = q    + (size_t)C_ * B_ * E_;          // C*B*H*E
    float* qb   = u    + (size_t)C_ * B_ * H_ * E_;     // C*B*H
    float* Z    = qb   + (size_t)C_ * B_ * H_;          // C*B*H
    float* S    = Z    + (size_t)C_ * B_ * H_;          // CB * SSZ
    size_t baseFloats = (size_t)(S - ws);

    // Batched-over-classes if workspace allows the full C-slice S buffer.
    size_t candFloats = (size_t)C_ * B_ * NCH * ns * 2;
    bool batched = ws_size >= (baseFloats + (size_t)C_ * SSZ + candFloats + 16) * 4;
    int CB = batched ? C_ : 1;
    float2* cand = (float2*)(S + (size_t)CB * SSZ);

    k_q<<<C_ * B_, 256, 0, stream>>>(x, Wq, bq, q);
    k_u<<<C_ * B_ * H_, 64, 0, stream>>>(q, Wk, bk, u, qb);

    dim3 gridS((N_ + BN - 1) / BN, (B_ * H_) / BM, CB);
    dim3 gridZ(B_ * H_, CB);
    dim3 gridT1(NCH, B_, CB);
    dim3 gridT2(B_, CB);
    for (int c0 = 0; c0 < C_; c0 += CB) {
        k_scores<<<gridS, 256, 0, stream>>>(u, qb, A, mask, S, c0);
        k_zred<<<gridZ, 256, 0, stream>>>(S, Z, c0);
        k_topk1<<<gridT1, 256, 0, stream>>>(S, Z, cand, c0, ns);
        k_topk2<<<gridT2, 256, 0, stream>>>(cand, out, c0, ns);
    }
}

// Round 4
// 604.594 us; speedup vs baseline: 3.6464x; 1.5364x over previous
//
#include <hip/hip_runtime.h>
#include <math.h>

// Problem constants (fixed by setup_inputs)
#define B_  32
#define N_  20000
#define C_  8
#define E_  512
#define H_  8
#define SCALE 0.125f   // 1/sqrt(64)

#define CHUNK 512
#define NCH   40       // ceil(20000/512)  (top-k chunking)
#define NC2   313      // ceil(20000/64)   (GEMM n-chunks)
#define SSZ ((size_t)B_ * H_ * N_)   // per-class S floats (256*20000)

typedef __attribute__((ext_vector_type(8))) short bf8_t;   // 8 bf16 (4 VGPRs)
typedef __attribute__((ext_vector_type(4))) float f32x4;   // MFMA acc

// RNE round-to-bf16 on bit patterns
__device__ inline unsigned short bf_round(float x, float& fv) {
    unsigned int u = __float_as_uint(x);
    unsigned int r = (u + 0x7fffu + ((u >> 16) & 1u)) & 0xffff0000u;
    fv = __uint_as_float(r);
    return (unsigned short)(r >> 16);
}

// ---------------------------------------------------------------------------
// K1a: q(c,b,f) = sum_e x(b,e) * Wq[c][f,e] + bq[c][f]
// ---------------------------------------------------------------------------
__global__ void k_q(const float* __restrict__ x, const float* __restrict__ Wq,
                    const float* __restrict__ bq, float* __restrict__ q) {
    int c = blockIdx.x / B_;
    int b = blockIdx.x % B_;
    __shared__ float xs[E_];
    int tid = threadIdx.x;
    for (int i = tid; i < E_; i += 256) xs[i] = x[b * E_ + i];
    __syncthreads();
    int wave = tid >> 6, lane = tid & 63;
    const float* W = Wq + (size_t)c * E_ * E_;
    for (int f = wave; f < E_; f += 4) {
        const float* row = W + (size_t)f * E_;
        float s = 0.f;
        #pragma unroll
        for (int e0 = 0; e0 < E_; e0 += 64) s += row[e0 + lane] * xs[e0 + lane];
        #pragma unroll
        for (int off = 32; off > 0; off >>= 1) s += __shfl_down(s, off, 64);
        if (lane == 0) q[((size_t)c * B_ + b) * E_ + f] = s + bq[c * E_ + f];
    }
}

// ---------------------------------------------------------------------------
// K1b: u(c,m,e) = sum_d q(c,b,h*64+d) * Wk[c][h*64+d, e]  (m = b*H+h)
//      qb(c,m)  = q·bk per head
// ---------------------------------------------------------------------------
__global__ void k_u(const float* __restrict__ q, const float* __restrict__ Wk,
                    const float* __restrict__ bk, float* __restrict__ u,
                    float* __restrict__ qb) {
    int idx = blockIdx.x;             // c*(B*H) + b*H + h
    int c  = idx / (B_ * H_);
    int bh = idx % (B_ * H_);
    int b  = bh / H_;
    int h  = bh % H_;
    int lane = threadIdx.x;
    __shared__ float qs[64];
    float qv = q[((size_t)c * B_ + b) * E_ + h * 64 + lane];
    qs[lane] = qv;
    float s = qv * bk[c * E_ + h * 64 + lane];
    #pragma unroll
    for (int off = 32; off > 0; off >>= 1) s += __shfl_down(s, off, 64);
    __syncthreads();
    const float* W = Wk + (size_t)c * E_ * E_ + (size_t)(h * 64) * E_;
    float* urow = u + (size_t)idx * E_;
    for (int e0 = 0; e0 < E_; e0 += 64) {
        float acc = 0.f;
        #pragma unroll 8
        for (int d = 0; d < 64; ++d) acc += qs[d] * W[(size_t)d * E_ + e0 + lane];
        urow[e0 + lane] = acc;
    }
    if (lane == 0) qb[idx] = s;
}

// ---------------------------------------------------------------------------
// Split u into 3 bf16 planes in MFMA A-fragment order:
//   u3[plane][c][mtile 16][kstep 16][512]; lane*8+j holds
//   u[c][mtile*16 + (lane&15)][kstep*32 + (lane>>4)*8 + j]
// ---------------------------------------------------------------------------
#define U3_PLANE ((size_t)C_ * 16 * 16 * 512)   // 1,048,576 shorts

__global__ void k_split_u3(const float* __restrict__ u, short* __restrict__ u3) {
    int bx = blockIdx.x;
    int ks = bx & 15, mt = (bx >> 4) & 15, c = bx >> 8;
    int lane = threadIdx.x;
    int m  = mt * 16 + (lane & 15);
    int k0 = ks * 32 + (lane >> 4) * 8;
    const float* up = u + ((size_t)c * 256 + m) * 512 + k0;
    size_t base = ((((size_t)c * 16 + mt) * 16 + ks) * 512) + (size_t)lane * 8;
    #pragma unroll
    for (int j = 0; j < 8; ++j) {
        float x = up[j], fh, fm, fl;
        unsigned short h = bf_round(x, fh);
        unsigned short mm = bf_round(x - fh, fm);
        unsigned short l = bf_round(x - fh - fm, fl);
        u3[base + j]                = (short)h;
        u3[U3_PLANE + base + j]     = (short)mm;
        u3[2 * U3_PLANE + base + j] = (short)l;
    }
}

// ---------------------------------------------------------------------------
// Split A into 3 bf16 planes, tiled per (nchunk, kstep): [3][64 n][32 k]
// (6144 shorts = 12288 B per tile). Staging in the GEMM is a straight copy.
// ---------------------------------------------------------------------------
__global__ void k_split_A3(const float* __restrict__ A, short* __restrict__ A3t) {
    int nc = blockIdx.x, ks = blockIdx.y;
    int tid = threadIdx.x;
    short* outp = A3t + ((size_t)nc * 16 + ks) * 6144;
    for (int e = tid; e < 2048; e += 256) {
        int n = e >> 5, kk = e & 31;
        int gn = nc * 64 + n;
        float x = (gn < N_) ? A[(size_t)gn * 512 + ks * 32 + kk] : 0.f;
        float fh, fm, fl;
        unsigned short h = bf_round(x, fh);
        unsigned short mm = bf_round(x - fh, fm);
        unsigned short l = bf_round(x - fh - fm, fl);
        outp[e]        = (short)h;
        outp[2048 + e] = (short)mm;
        outp[4096 + e] = (short)l;
    }
}

// ---------------------------------------------------------------------------
// Main: S(m,n) = member ? exp(SCALE*(u·A + qb)) : 0, via 6-product bf16x3 MFMA.
// Block: 256 thr (4 waves), tile M=256 (full) x BN=64, one (class, nchunk).
// Wave w owns m-rows [w*64, w*64+64). Fused per-block row-sum -> Zpart.
// grid.x = NC2 * CB, class-fastest for A-tile L2 reuse.
// ---------------------------------------------------------------------------
#define MFMA16(a, b, c) __builtin_amdgcn_mfma_f32_16x16x32_bf16(a, b, c, 0, 0, 0)

__global__ __launch_bounds__(256) void k_scores_mfma(
        const short* __restrict__ u3, const short* __restrict__ A3t,
        const float* __restrict__ qb, const int* __restrict__ mask,
        float* __restrict__ S, float* __restrict__ Zpart, int c0, int CB) {
    __shared__ __align__(16) short As[3 * 64 * 40];   // plane stride 2560; row 40 (32+8 pad)
    __shared__ float sQb[256];
    __shared__ int   sMask[64];
    int bx = blockIdx.x;
    int z  = bx % CB;
    int c  = c0 + z;
    int nc = bx / CB;
    int tid = threadIdx.x;
    int lane = tid & 63, w = tid >> 6;
    int quad = lane >> 4, l15 = lane & 15;
    int n0 = nc * 64;

    sQb[tid] = qb[c * 256 + tid];
    if (tid < 64) {
        int n = n0 + tid;
        sMask[tid] = (n < N_) ? mask[(size_t)n * C_ + c] : 0;
    }

    f32x4 acc[4][4];
    #pragma unroll
    for (int i = 0; i < 4; ++i)
        #pragma unroll
        for (int j = 0; j < 4; ++j)
            acc[i][j] = (f32x4){0.f, 0.f, 0.f, 0.f};

    const char* tileBase = (const char*)A3t + (size_t)nc * (16 * 12288);

    for (int ks = 0; ks < 16; ++ks) {
        __syncthreads();
        // stage [3][64][32] -> LDS [3][64][40]. Plane row = 32 shorts = 4 float4s:
        // i = p*256 + r; src shorts p*2048 + r*8 -> row n=r>>2, quarter q4=r&3.
        const float4* src = (const float4*)(tileBase + (size_t)ks * 12288);
        for (int i = tid; i < 768; i += 256) {
            int p = i >> 8, r = i & 255, n = r >> 2, q4 = r & 3;
            *(float4*)&As[p * 2560 + n * 40 + q4 * 8] = src[i];
        }
        __syncthreads();

        bf8_t bf[4][3];
        #pragma unroll
        for (int nt = 0; nt < 4; ++nt)
            #pragma unroll
            for (int p = 0; p < 3; ++p)
                bf[nt][p] = *(const bf8_t*)&As[p * 2560 + (nt * 16 + l15) * 40 + quad * 8];

        #pragma unroll
        for (int mt = 0; mt < 4; ++mt) {
            int mtile = w * 4 + mt;
            size_t ub = ((((size_t)c * 16 + mtile) * 16 + ks) * 512) + (size_t)lane * 8;
            bf8_t af0 = *(const bf8_t*)(u3 + ub);
            bf8_t af1 = *(const bf8_t*)(u3 + U3_PLANE + ub);
            bf8_t af2 = *(const bf8_t*)(u3 + 2 * U3_PLANE + ub);
            #pragma unroll
            for (int nt = 0; nt < 4; ++nt) acc[mt][nt] = MFMA16(af0, bf[nt][0], acc[mt][nt]);
            #pragma unroll
            for (int nt = 0; nt < 4; ++nt) acc[mt][nt] = MFMA16(af0, bf[nt][1], acc[mt][nt]);
            #pragma unroll
            for (int nt = 0; nt < 4; ++nt) acc[mt][nt] = MFMA16(af1, bf[nt][0], acc[mt][nt]);
            #pragma unroll
            for (int nt = 0; nt < 4; ++nt) acc[mt][nt] = MFMA16(af1, bf[nt][1], acc[mt][nt]);
            #pragma unroll
            for (int nt = 0; nt < 4; ++nt) acc[mt][nt] = MFMA16(af0, bf[nt][2], acc[mt][nt]);
            #pragma unroll
            for (int nt = 0; nt < 4; ++nt) acc[mt][nt] = MFMA16(af2, bf[nt][0], acc[mt][nt]);
        }
    }

    // Epilogue: scale + bias + mask + exp, write S, fused deterministic row-sums.
    float* Sc = S + (size_t)z * SSZ;
    #pragma unroll
    for (int mt = 0; mt < 4; ++mt) {
        float rs0 = 0.f, rs1 = 0.f, rs2 = 0.f, rs3 = 0.f;
        #pragma unroll
        for (int nt = 0; nt < 4; ++nt) {
            int n = n0 + nt * 16 + l15;
            int mem = sMask[nt * 16 + l15];
            #pragma unroll
            for (int r = 0; r < 4; ++r) {
                int m = w * 64 + mt * 16 + quad * 4 + r;
                float sc = SCALE * (acc[mt][nt][r] + sQb[m]);
                float ev = mem ? __expf(sc) : 0.f;
                if (r == 0) rs0 += ev; else if (r == 1) rs1 += ev;
                else if (r == 2) rs2 += ev; else rs3 += ev;
                if (n < N_) Sc[(size_t)m * N_ + n] = ev;
            }
        }
        #pragma unroll
        for (int r = 0; r < 4; ++r) {
            float v = (r == 0) ? rs0 : (r == 1) ? rs1 : (r == 2) ? rs2 : rs3;
            v += __shfl_xor(v, 1); v += __shfl_xor(v, 2);
            v += __shfl_xor(v, 4); v += __shfl_xor(v, 8);
            if (l15 == 0) {
                int m = w * 64 + mt * 16 + quad * 4 + r;
                Zpart[((size_t)nc * C_ + c) * 256 + m] = v;
            }
        }
    }
}

// ---------------------------------------------------------------------------
// Z(c,m) = sum_nc Zpart(nc,c,m). grid = CB blocks x 256 thr.
// ---------------------------------------------------------------------------
__global__ void k_zsum(const float* __restrict__ Zpart, float* __restrict__ Z, int c0) {
    int c = c0 + blockIdx.x;
    int i = c * 256 + threadIdx.x;
    float s = 0.f;
    for (int nc = 0; nc < NC2; ++nc) s += Zpart[(size_t)nc * (C_ * 256) + i];
    Z[i] = s;
}

// ---------------------------------------------------------------------------
// K3: fused head-average + chunk-local top-ns. grid (NCH, B, CB).
// ---------------------------------------------------------------------------
__global__ __launch_bounds__(256) void k_topk1(
        const float* __restrict__ S, const float* __restrict__ Z,
        float2* __restrict__ cand, int c0, int ns) {
    int chunk = blockIdx.x, b = blockIdx.y, z = blockIdx.z;
    const float* Sc = S + (size_t)z * SSZ;
    int tid = threadIdx.x;
    __shared__ float zr[H_];
    if (tid < H_) zr[tid] = 1.0f / Z[(c0 + z) * (B_ * H_) + b * H_ + tid];
    __syncthreads();
    int n0 = chunk * CHUNK;
    float v[2]; int ix[2];
    #pragma unroll
    for (int s = 0; s < 2; ++s) {
        int n = n0 + tid + s * 256;
        float a = -1.f;
        if (n < N_) {
            a = 0.f;
            #pragma unroll
            for (int h = 0; h < H_; ++h)
                a += Sc[(size_t)(b * H_ + h) * N_ + n] * zr[h];
            a *= (1.0f / H_);
        }
        v[s] = a; ix[s] = (n < N_) ? n : N_;
    }
    __shared__ float sv[256];
    __shared__ int   si[256];
    __shared__ int   win;
    for (int j = 0; j < ns; ++j) {
        float bv; int bi;
        if (v[0] > v[1] || (v[0] == v[1] && ix[0] < ix[1])) { bv = v[0]; bi = ix[0]; }
        else                                                 { bv = v[1]; bi = ix[1]; }
        sv[tid] = bv; si[tid] = bi;
        __syncthreads();
        for (int w = 128; w >= 1; w >>= 1) {
            if (tid < w) {
                float v2 = sv[tid + w]; int i2 = si[tid + w];
                if (v2 > sv[tid] || (v2 == sv[tid] && i2 < si[tid])) {
                    sv[tid] = v2; si[tid] = i2;
                }
            }
            __syncthreads();
        }
        if (tid == 0) {
            cand[(((size_t)z * B_ + b) * NCH + chunk) * ns + j] =
                make_float2(sv[0], (float)si[0]);
            win = si[0];
        }
        __syncthreads();
        if (ix[0] == win) v[0] = -2.f;
        if (ix[1] == win) v[1] = -2.f;
        __syncthreads();
    }
}

// ---------------------------------------------------------------------------
// K4: merge NCH*ns candidates -> final top-ns per (b, class). grid (B, CB).
// ---------------------------------------------------------------------------
__global__ __launch_bounds__(256) void k_topk2(
        const float2* __restrict__ cand, float* __restrict__ out, int c0, int ns) {
    int b = blockIdx.x, z = blockIdx.y;
    int c = c0 + z;
    int tid = threadIdx.x;
    int ncand = NCH * ns;
    const float2* cb = cand + ((size_t)z * B_ + b) * ncand;
    float v = -3.f; int ix = N_ + 1;
    if (tid < ncand) { float2 e = cb[tid]; v = e.x; ix = (int)e.y; }
    __shared__ float sv[256];
    __shared__ int   si[256];
    __shared__ int   win;
    for (int j = 0; j < ns; ++j) {
        sv[tid] = v; si[tid] = ix;
        __syncthreads();
        for (int w = 128; w >= 1; w >>= 1) {
            if (tid < w) {
                float v2 = sv[tid + w]; int i2 = si[tid + w];
                if (v2 > sv[tid] || (v2 == sv[tid] && i2 < si[tid])) {
                    sv[tid] = v2; si[tid] = i2;
                }
            }
            __syncthreads();
        }
        if (tid == 0) {
            out[((size_t)b * C_ + c) * ns + j] = (float)si[0];
            out[(size_t)B_ * C_ * ns + ((size_t)b * C_ + c) * ns + j] = sv[0];
            win = si[0];
        }
        __syncthreads();
        if (ix == win) v = -3.f;
        __syncthreads();
    }
}

// ---------------------------------------------------------------------------
extern "C" void kernel_launch(void* const* d_in, const int* in_sizes, int n_in,
                              void* d_out, int out_size, void* d_ws, size_t ws_size,
                              hipStream_t stream) {
    const float* x    = (const float*)d_in[0];  // (B,E)
    const float* A    = (const float*)d_in[1];  // (N,E)
    const int*   mask = (const int*)  d_in[2];  // (N,C)
    const float* Wq   = (const float*)d_in[3];  // (C,E,E)
    const float* bq   = (const float*)d_in[4];  // (C,E)
    const float* Wk   = (const float*)d_in[5];  // (C,E,E)
    const float* bk   = (const float*)d_in[6];  // (C,E)
    float* out = (float*)d_out;

    int ns = out_size / (2 * B_ * C_);          // = n_samples (5)

    // Workspace carve (floats)
    float* ws = (float*)d_ws;
    float* q     = ws;                                    // 131072
    float* u     = q     + (size_t)C_ * B_ * E_;          // 1048576
    float* qb    = u     + (size_t)C_ * B_ * H_ * E_;     // 2048
    float* Z     = qb    + (size_t)C_ * B_ * H_;          // 2048
    float* Zpart = Z     + (size_t)C_ * B_ * H_;          // NC2*8*256 = 641024
    short* u3    = (short*)(Zpart + (size_t)NC2 * C_ * 256);      // 3*1048576 shorts
    short* A3t   = u3 + 3 * U3_PLANE;                             // NC2*16*6144 shorts
    float* S     = (float*)(A3t + (size_t)NC2 * 16 * 6144);
    size_t fixedFloats = (size_t)(S - ws);

    size_t candFloats = (size_t)C_ * B_ * NCH * ns * 2;
    int CB = 8;
    while (CB > 1 &&
           (fixedFloats + (size_t)CB * SSZ + candFloats + 16) * 4 > ws_size)
        CB >>= 1;
    float2* cand = (float2*)(S + (size_t)CB * SSZ);

    k_q<<<C_ * B_, 256, 0, stream>>>(x, Wq, bq, q);
    k_u<<<C_ * B_ * H_, 64, 0, stream>>>(q, Wk, bk, u, qb);
    k_split_u3<<<C_ * 16 * 16, 64, 0, stream>>>(u, u3);
    k_split_A3<<<dim3(NC2, 16), 256, 0, stream>>>(A, A3t);

    for (int c0 = 0; c0 < C_; c0 += CB) {
        k_scores_mfma<<<NC2 * CB, 256, 0, stream>>>(u3, A3t, qb, mask, S, Zpart, c0, CB);
        k_zsum<<<CB, 256, 0, stream>>>(Zpart, Z, c0);
        k_topk1<<<dim3(NCH, B_, CB), 256, 0, stream>>>(S, Z, cand, c0, ns);
        k_topk2<<<dim3(B_, CB), 256, 0, stream>>>(cand, out, c0, ns);
    }
}

// Round 5
// 458.208 us; speedup vs baseline: 4.8113x; 1.3195x over previous
//
#include <hip/hip_runtime.h>
#include <math.h>

// Problem constants (fixed by setup_inputs)
#define B_  32
#define N_  20000
#define C_  8
#define E_  512
#define H_  8
#define SCALE 0.125f   // 1/sqrt(64)

#define CHUNK 512
#define NCH   40       // ceil(20000/512)  (top-k chunking)
#define NC3   157      // ceil(20000/128)  (GEMM n-chunks, BN=128)
#define SSZ ((size_t)B_ * H_ * N_)   // per-class S floats (256*20000)

typedef __attribute__((ext_vector_type(8))) short bf8_t;   // 8 bf16 (4 VGPRs)
typedef __attribute__((ext_vector_type(4))) float f32x4;   // MFMA acc

// RNE round-to-bf16 on bit patterns
__device__ inline unsigned short bf_round(float x, float& fv) {
    unsigned int u = __float_as_uint(x);
    unsigned int r = (u + 0x7fffu + ((u >> 16) & 1u)) & 0xffff0000u;
    fv = __uint_as_float(r);
    return (unsigned short)(r >> 16);
}

// ---------------------------------------------------------------------------
// K1a: q(c,b,f) = sum_e x(b,e) * Wq[c][f,e] + bq[c][f]
// Weight-stationary: block = (f-tile of 8, c); thread = (b, f_sub).
// All LDS reads broadcast or 2-way (rows padded to 66). Wq read exactly once.
// ---------------------------------------------------------------------------
__global__ __launch_bounds__(256) void k_q2(
        const float* __restrict__ x, const float* __restrict__ Wq,
        const float* __restrict__ bq, float* __restrict__ q) {
    int ft = blockIdx.x, c = blockIdx.y;
    int f0 = ft * 8;
    __shared__ float wsm[8][66];
    __shared__ float xs[32][66];
    int tid = threadIdx.x;
    int b = tid & 31, fs = tid >> 5;
    float acc = 0.f;
    const float* W = Wq + (size_t)c * E_ * E_;
    for (int k0 = 0; k0 < E_; k0 += 64) {
        __syncthreads();
        for (int i = tid; i < 512; i += 256)
            wsm[i >> 6][i & 63] = W[(size_t)(f0 + (i >> 6)) * E_ + k0 + (i & 63)];
        for (int i = tid; i < 2048; i += 256)
            xs[i >> 6][i & 63] = x[(size_t)(i >> 6) * E_ + k0 + (i & 63)];
        __syncthreads();
        #pragma unroll
        for (int kk = 0; kk < 64; ++kk)
            acc += xs[b][kk] * wsm[fs][kk];
    }
    q[((size_t)c * B_ + b) * E_ + f0 + fs] = acc + bq[c * E_ + f0 + fs];
}

// ---------------------------------------------------------------------------
// K1b: u(c, m=(b*8+h), e) = sum_d q(c,b,h*64+d) * Wk[c][h*64+d, e]
// block = (e-tile of 64, h, c); thread = (b, e-group of 8). Wk read once.
// Also computes qb(c,m) = q·bk (et==0, es==0 threads).
// ---------------------------------------------------------------------------
__global__ __launch_bounds__(256) void k_u2(
        const float* __restrict__ q, const float* __restrict__ Wk,
        const float* __restrict__ bk, float* __restrict__ u,
        float* __restrict__ qb) {
    int et = blockIdx.x, h = blockIdx.y, c = blockIdx.z;
    int e0 = et * 64;
    __shared__ float qs[32][66];
    __shared__ float wk[64][66];
    int tid = threadIdx.x;
    int b = tid & 31, es = tid >> 5;
    for (int i = tid; i < 2048; i += 256)
        qs[i >> 6][i & 63] = q[((size_t)c * B_ + (i >> 6)) * E_ + h * 64 + (i & 63)];
    const float* W = Wk + (size_t)c * E_ * E_ + (size_t)(h * 64) * E_;
    for (int i = tid; i < 4096; i += 256)
        wk[i >> 6][i & 63] = W[(size_t)(i >> 6) * E_ + e0 + (i & 63)];
    __syncthreads();
    float acc[8] = {};
    for (int d = 0; d < 64; ++d) {
        float qv = qs[b][d];
        #pragma unroll
        for (int j = 0; j < 8; ++j)
            acc[j] += qv * wk[d][es * 8 + j];
    }
    float* urow = u + ((size_t)c * 256 + b * 8 + h) * E_ + e0 + es * 8;
    #pragma unroll
    for (int j = 0; j < 8; ++j) urow[j] = acc[j];
    if (et == 0 && es == 0) {
        float s = 0.f;
        const float* bkr = bk + c * E_ + h * 64;
        for (int d = 0; d < 64; ++d) s += qs[b][d] * bkr[d];
        qb[c * 256 + b * 8 + h] = s;
    }
}

// ---------------------------------------------------------------------------
// Split u into 3 bf16 planes in MFMA A-fragment order:
//   u3[plane][c][mtile 16][kstep 16][512]; lane*8+j holds
//   u[c][mtile*16 + (lane&15)][kstep*32 + (lane>>4)*8 + j]
// ---------------------------------------------------------------------------
#define U3_PLANE ((size_t)C_ * 16 * 16 * 512)   // 1,048,576 shorts

__global__ void k_split_u3(const float* __restrict__ u, short* __restrict__ u3) {
    int bx = blockIdx.x;
    int ks = bx & 15, mt = (bx >> 4) & 15, c = bx >> 8;
    int lane = threadIdx.x;
    int m  = mt * 16 + (lane & 15);
    int k0 = ks * 32 + (lane >> 4) * 8;
    const float* up = u + ((size_t)c * 256 + m) * 512 + k0;
    size_t base = ((((size_t)c * 16 + mt) * 16 + ks) * 512) + (size_t)lane * 8;
    #pragma unroll
    for (int j = 0; j < 8; ++j) {
        float x = up[j], fh, fm, fl;
        unsigned short h = bf_round(x, fh);
        unsigned short mm = bf_round(x - fh, fm);
        unsigned short l = bf_round(x - fh - fm, fl);
        u3[base + j]                = (short)h;
        u3[U3_PLANE + base + j]     = (short)mm;
        u3[2 * U3_PLANE + base + j] = (short)l;
    }
}

// ---------------------------------------------------------------------------
// Split A into 3 bf16 planes, tiled per (nchunk of 128, kstep of 32):
//   [3][128 n][32 k], 12288 shorts (24576 B) per tile, with within-row
//   16B-chunk swizzle: chunk q4 of row n stored at position (q4 + (n>>1))&3.
// GEMM staging is then a straight linear 24 KB copy (conflict-free) and the
// swizzled b128 frag reads are <=2-way (free).
// ---------------------------------------------------------------------------
__global__ void k_split_A3(const float* __restrict__ A, short* __restrict__ A3t) {
    int nc = blockIdx.x, ks = blockIdx.y;
    int tid = threadIdx.x;
    short* outp = A3t + ((size_t)nc * 16 + ks) * 12288;
    for (int e = tid; e < 4096; e += 256) {
        int n = e >> 5, kk = e & 31;
        int gn = nc * 128 + n;
        float x = (gn < N_) ? A[(size_t)gn * 512 + ks * 32 + kk] : 0.f;
        float fh, fm, fl;
        unsigned short h = bf_round(x, fh);
        unsigned short mm = bf_round(x - fh, fm);
        unsigned short l = bf_round(x - fh - fm, fl);
        int q4 = kk >> 3, jj = kk & 7;
        int pos = n * 32 + ((q4 + (n >> 1)) & 3) * 8 + jj;
        outp[pos]        = (short)h;
        outp[4096 + pos] = (short)mm;
        outp[8192 + pos] = (short)l;
    }
}

// ---------------------------------------------------------------------------
// Main: S(m,n) = member ? exp(SCALE*(u·A + qb)) : 0, via 6-product bf16x3 MFMA.
// Block: 256 thr (4 waves), tile M=256 (full) x BN=128, one (class, nchunk).
// Wave w owns m-rows [w*64, w*64+64) x all 128 n: 192 MFMA per ks-step.
// Fused per-block row-sums -> Zpart. grid.x = NC3*CB, class-fastest.
// ---------------------------------------------------------------------------
#define MFMA16(a, b, c) __builtin_amdgcn_mfma_f32_16x16x32_bf16(a, b, c, 0, 0, 0)

__global__ __launch_bounds__(256, 2) void k_scores_mfma(
        const short* __restrict__ u3, const short* __restrict__ A3t,
        const float* __restrict__ qb, const int* __restrict__ mask,
        float* __restrict__ S, float* __restrict__ Zpart, int c0, int CB) {
    __shared__ __align__(16) short As[12288];   // [3][128][32] swizzled
    __shared__ float sQb[256];
    __shared__ int   sMask[128];
    int bx = blockIdx.x;
    int z  = bx % CB;
    int c  = c0 + z;
    int nc = bx / CB;
    int tid = threadIdx.x;
    int lane = tid & 63, w = tid >> 6;
    int quad = lane >> 4, l15 = lane & 15;
    int n0 = nc * 128;

    sQb[tid] = qb[c * 256 + tid];
    if (tid < 128) {
        int n = n0 + tid;
        sMask[tid] = (n < N_) ? mask[(size_t)n * C_ + c] : 0;
    }

    f32x4 acc[4][8];
    #pragma unroll
    for (int i = 0; i < 4; ++i)
        #pragma unroll
        for (int j = 0; j < 8; ++j)
            acc[i][j] = (f32x4){0.f, 0.f, 0.f, 0.f};

    const char* tileBase = (const char*)A3t + (size_t)nc * (16 * 24576);

    for (int ks = 0; ks < 16; ++ks) {
        __syncthreads();
        const float4* src = (const float4*)(tileBase + (size_t)ks * 24576);
        float4* dst = (float4*)As;
        #pragma unroll
        for (int t = 0; t < 6; ++t) dst[tid + t * 256] = src[tid + t * 256];
        __syncthreads();

        bf8_t af[4][3];
        #pragma unroll
        for (int mt = 0; mt < 4; ++mt) {
            size_t ub = ((((size_t)c * 16 + (w * 4 + mt)) * 16 + ks) * 512)
                        + (size_t)lane * 8;
            af[mt][0] = *(const bf8_t*)(u3 + ub);
            af[mt][1] = *(const bf8_t*)(u3 + U3_PLANE + ub);
            af[mt][2] = *(const bf8_t*)(u3 + 2 * U3_PLANE + ub);
        }
        #pragma unroll
        for (int nt = 0; nt < 8; ++nt) {
            int r = nt * 16 + l15;
            const short* bp = &As[r * 32 + ((quad + (r >> 1)) & 3) * 8];
            bf8_t b0 = *(const bf8_t*)bp;
            bf8_t b1 = *(const bf8_t*)(bp + 4096);
            bf8_t b2 = *(const bf8_t*)(bp + 8192);
            #pragma unroll
            for (int mt = 0; mt < 4; ++mt) {
                f32x4 a = acc[mt][nt];
                a = MFMA16(af[mt][0], b0, a);   // hh
                a = MFMA16(af[mt][0], b1, a);   // hm
                a = MFMA16(af[mt][1], b0, a);   // mh
                a = MFMA16(af[mt][1], b1, a);   // mm
                a = MFMA16(af[mt][0], b2, a);   // hl
                a = MFMA16(af[mt][2], b0, a);   // lh
                acc[mt][nt] = a;
            }
        }
    }

    // Epilogue: scale + bias + mask + exp, write S, fused deterministic row-sums.
    float* Sc = S + (size_t)z * SSZ;
    #pragma unroll
    for (int mt = 0; mt < 4; ++mt) {
        float rs[4] = {0.f, 0.f, 0.f, 0.f};
        #pragma unroll
        for (int nt = 0; nt < 8; ++nt) {
            int n = n0 + nt * 16 + l15;
            int mem = sMask[nt * 16 + l15];
            #pragma unroll
            for (int r = 0; r < 4; ++r) {
                int m = w * 64 + mt * 16 + quad * 4 + r;
                float sc = SCALE * (acc[mt][nt][r] + sQb[m]);
                float ev = mem ? __expf(sc) : 0.f;
                rs[r] += ev;
                if (n < N_) Sc[(size_t)m * N_ + n] = ev;
            }
        }
        #pragma unroll
        for (int r = 0; r < 4; ++r) {
            float v = rs[r];
            v += __shfl_xor(v, 1); v += __shfl_xor(v, 2);
            v += __shfl_xor(v, 4); v += __shfl_xor(v, 8);
            if (l15 == 0) {
                int m = w * 64 + mt * 16 + quad * 4 + r;
                Zpart[((size_t)nc * C_ + c) * 256 + m] = v;
            }
        }
    }
}

// ---------------------------------------------------------------------------
// Z(c,m) = sum_nc Zpart(nc,c,m). grid = CB blocks x 256 thr.
// ---------------------------------------------------------------------------
__global__ void k_zsum(const float* __restrict__ Zpart, float* __restrict__ Z, int c0) {
    int c = c0 + blockIdx.x;
    int i = c * 256 + threadIdx.x;
    float s = 0.f;
    for (int nc = 0; nc < NC3; ++nc) s += Zpart[(size_t)nc * (C_ * 256) + i];
    Z[i] = s;
}

// ---------------------------------------------------------------------------
// K3: fused head-average + chunk-local top-ns. grid (NCH, B, CB).
// ---------------------------------------------------------------------------
__global__ __launch_bounds__(256) void k_topk1(
        const float* __restrict__ S, const float* __restrict__ Z,
        float2* __restrict__ cand, int c0, int ns) {
    int chunk = blockIdx.x, b = blockIdx.y, z = blockIdx.z;
    const float* Sc = S + (size_t)z * SSZ;
    int tid = threadIdx.x;
    __shared__ float zr[H_];
    if (tid < H_) zr[tid] = 1.0f / Z[(c0 + z) * (B_ * H_) + b * H_ + tid];
    __syncthreads();
    int n0 = chunk * CHUNK;
    float v[2]; int ix[2];
    #pragma unroll
    for (int s = 0; s < 2; ++s) {
        int n = n0 + tid + s * 256;
        float a = -1.f;
        if (n < N_) {
            a = 0.f;
            #pragma unroll
            for (int h = 0; h < H_; ++h)
                a += Sc[(size_t)(b * H_ + h) * N_ + n] * zr[h];
            a *= (1.0f / H_);
        }
        v[s] = a; ix[s] = (n < N_) ? n : N_;
    }
    __shared__ float sv[256];
    __shared__ int   si[256];
    __shared__ int   win;
    for (int j = 0; j < ns; ++j) {
        float bv; int bi;
        if (v[0] > v[1] || (v[0] == v[1] && ix[0] < ix[1])) { bv = v[0]; bi = ix[0]; }
        else                                                 { bv = v[1]; bi = ix[1]; }
        sv[tid] = bv; si[tid] = bi;
        __syncthreads();
        for (int w = 128; w >= 1; w >>= 1) {
            if (tid < w) {
                float v2 = sv[tid + w]; int i2 = si[tid + w];
                if (v2 > sv[tid] || (v2 == sv[tid] && i2 < si[tid])) {
                    sv[tid] = v2; si[tid] = i2;
                }
            }
            __syncthreads();
        }
        if (tid == 0) {
            cand[(((size_t)z * B_ + b) * NCH + chunk) * ns + j] =
                make_float2(sv[0], (float)si[0]);
            win = si[0];
        }
        __syncthreads();
        if (ix[0] == win) v[0] = -2.f;
        if (ix[1] == win) v[1] = -2.f;
        __syncthreads();
    }
}

// ---------------------------------------------------------------------------
// K4: merge NCH*ns candidates -> final top-ns per (b, class). grid (B, CB).
// ---------------------------------------------------------------------------
__global__ __launch_bounds__(256) void k_topk2(
        const float2* __restrict__ cand, float* __restrict__ out, int c0, int ns) {
    int b = blockIdx.x, z = blockIdx.y;
    int c = c0 + z;
    int tid = threadIdx.x;
    int ncand = NCH * ns;
    const float2* cb = cand + ((size_t)z * B_ + b) * ncand;
    float v = -3.f; int ix = N_ + 1;
    if (tid < ncand) { float2 e = cb[tid]; v = e.x; ix = (int)e.y; }
    __shared__ float sv[256];
    __shared__ int   si[256];
    __shared__ int   win;
    for (int j = 0; j < ns; ++j) {
        sv[tid] = v; si[tid] = ix;
        __syncthreads();
        for (int w = 128; w >= 1; w >>= 1) {
            if (tid < w) {
                float v2 = sv[tid + w]; int i2 = si[tid + w];
                if (v2 > sv[tid] || (v2 == sv[tid] && i2 < si[tid])) {
                    sv[tid] = v2; si[tid] = i2;
                }
            }
            __syncthreads();
        }
        if (tid == 0) {
            out[((size_t)b * C_ + c) * ns + j] = (float)si[0];
            out[(size_t)B_ * C_ * ns + ((size_t)b * C_ + c) * ns + j] = sv[0];
            win = si[0];
        }
        __syncthreads();
        if (ix == win) v = -3.f;
        __syncthreads();
    }
}

// ---------------------------------------------------------------------------
extern "C" void kernel_launch(void* const* d_in, const int* in_sizes, int n_in,
                              void* d_out, int out_size, void* d_ws, size_t ws_size,
                              hipStream_t stream) {
    const float* x    = (const float*)d_in[0];  // (B,E)
    const float* A    = (const float*)d_in[1];  // (N,E)
    const int*   mask = (const int*)  d_in[2];  // (N,C)
    const float* Wq   = (const float*)d_in[3];  // (C,E,E)
    const float* bq   = (const float*)d_in[4];  // (C,E)
    const float* Wk   = (const float*)d_in[5];  // (C,E,E)
    const float* bk   = (const float*)d_in[6];  // (C,E)
    float* out = (float*)d_out;

    int ns = out_size / (2 * B_ * C_);          // = n_samples (5)

    // Workspace carve (floats)
    float* ws = (float*)d_ws;
    float* q     = ws;                                    // 131072
    float* u     = q     + (size_t)C_ * B_ * E_;          // 1048576
    float* qb    = u     + (size_t)C_ * B_ * H_ * E_;     // 2048
    float* Z     = qb    + (size_t)C_ * B_ * H_;          // 2048
    float* Zpart = Z     + (size_t)C_ * B_ * H_;          // NC3*8*256 = 321536
    short* u3    = (short*)(Zpart + (size_t)NC3 * C_ * 256);   // 3*1048576 shorts
    short* A3t   = u3 + 3 * U3_PLANE;                          // NC3*16*12288 shorts
    float* S     = (float*)(A3t + (size_t)NC3 * 16 * 12288);
    size_t fixedFloats = (size_t)(S - ws);

    size_t candFloats = (size_t)C_ * B_ * NCH * ns * 2;
    int CB = 8;
    while (CB > 1 &&
           (fixedFloats + (size_t)CB * SSZ + candFloats + 16) * 4 > ws_size)
        CB >>= 1;
    float2* cand = (float2*)(S + (size_t)CB * SSZ);

    k_q2<<<dim3(64, C_), 256, 0, stream>>>(x, Wq, bq, q);
    k_u2<<<dim3(8, H_, C_), 256, 0, stream>>>(q, Wk, bk, u, qb);
    k_split_u3<<<C_ * 16 * 16, 64, 0, stream>>>(u, u3);
    k_split_A3<<<dim3(NC3, 16), 256, 0, stream>>>(A, A3t);

    for (int c0 = 0; c0 < C_; c0 += CB) {
        k_scores_mfma<<<NC3 * CB, 256, 0, stream>>>(u3, A3t, qb, mask, S, Zpart, c0, CB);
        k_zsum<<<CB, 256, 0, stream>>>(Zpart, Z, c0);
        k_topk1<<<dim3(NCH, B_, CB), 256, 0, stream>>>(S, Z, cand, c0, ns);
        k_topk2<<<dim3(B_, CB), 256, 0, stream>>>(cand, out, c0, ns);
    }
}